// Round 1
// baseline (150.793 us; speedup 1.0000x reference)
//
#include <hip/hip_runtime.h>

#define BB 8192
#define GG 32
#define DD 64

__global__ __launch_bounds__(64, 4)
void hhgr_kernel(const int* __restrict__ group_inputs,
                 const int* __restrict__ item_inputs,
                 const int* __restrict__ members,
                 const float* __restrict__ user_table,
                 const float* __restrict__ item_table,
                 const float* __restrict__ group_table,
                 const float* __restrict__ group_embedds,
                 const float* __restrict__ att_w1, const float* __restrict__ att_b1,
                 const float* __restrict__ att_w2, const float* __restrict__ att_b2,
                 const float* __restrict__ cls_w, const float* __restrict__ cls_b,
                 const float* __restrict__ pred_w1, const float* __restrict__ pred_b1,
                 const float* __restrict__ pred_w2, const float* __restrict__ pred_b2,
                 float* __restrict__ out)
{
    // LDS layout (floats): mem[32][68] | item[64] | score[32] | awt[32]; ne[192] aliases mem
    __shared__ float smem[2176 + 64 + 32 + 32];
    float* mem_lds   = smem;
    float* item_lds  = smem + 2176;
    float* score_lds = smem + 2240;
    float* awt_lds   = smem + 2272;
    float* ne_lds    = smem;        // reused after mem_lds is consumed

    const int b    = blockIdx.x;
    const int lane = threadIdx.x;          // 0..63
    const int o    = lane & 15;            // attention hidden unit
    const int q    = lane >> 4;            // 0..3
    const int h2   = q & 1;                // k-half for layer-1 mem dot
    const int gg   = q >> 1;               // member sub-index within a g-batch

    const int gidx = group_inputs[b];
    const int iidx = item_inputs[b];
    const int midx = members[b * GG + (lane & 31)];

    // ---- gather item embedding (coalesced) ----
    const float it = item_table[(size_t)iidx * DD + lane];
    item_lds[lane] = it;

    // ---- gather 32 member rows -> LDS (4 rows per dwordx4 wave-load) ----
#pragma unroll
    for (int i = 0; i < 8; ++i) {
        const int r   = 4 * i + q;                       // row 0..31
        const int row = __shfl(midx, r);
        const float4 v = *(const float4*)(user_table + (size_t)row * DD + o * 4);
        *(float4*)(mem_lds + r * 68 + o * 4) = v;
    }

    // ---- preload this lane's att_w1 column half into registers ----
    float wl[32];
#pragma unroll
    for (int j = 0; j < 32; ++j)
        wl[j] = att_w1[(h2 * 32 + j) * 16 + o];
    const float w2v = att_w2[o];
    const float b2  = att_b2[0];

    __syncthreads();

    // ---- item half of layer 1 (shared across all members) + b1 ----
    float hiacc = 0.f;
#pragma unroll
    for (int k2 = 0; k2 < 16; ++k2) {
        const int k = q * 16 + k2;
        hiacc = fmaf(item_lds[k], att_w1[(64 + k) * 16 + o], hiacc);
    }
    hiacc += __shfl_xor(hiacc, 16);
    hiacc += __shfl_xor(hiacc, 32);
    const float hib = hiacc + att_b1[o];

    // ---- main attention loop: 2 members per iteration ----
    for (int gb = 0; gb < 16; ++gb) {
        const int g = gb * 2 + gg;
        const float* mrow = mem_lds + g * 68 + h2 * 32;
        float acc = 0.f;
#pragma unroll
        for (int i = 0; i < 8; ++i) {
            const float4 m4 = *(const float4*)(mrow + i * 4);
            acc = fmaf(m4.x, wl[i * 4 + 0], acc);
            acc = fmaf(m4.y, wl[i * 4 + 1], acc);
            acc = fmaf(m4.z, wl[i * 4 + 2], acc);
            acc = fmaf(m4.w, wl[i * 4 + 3], acc);
        }
        acc += __shfl_xor(acc, 16);                 // combine k-halves
        const float h = fmaxf(acc + hib, 0.f);      // relu(mem·W + item·W + b1)
        float c = h * w2v;
        c += __shfl_xor(c, 1);
        c += __shfl_xor(c, 2);
        c += __shfl_xor(c, 4);
        c += __shfl_xor(c, 8);                      // sum over 16 hidden units
        if ((lane & 31) == 0) score_lds[g] = c + b2;
    }
    __syncthreads();

    // ---- softmax over 32 members (replicated in both wave halves) ----
    const int gl = lane & 31;
    const float s = score_lds[gl];
    float m = s;
#pragma unroll
    for (int mk = 1; mk <= 16; mk <<= 1) m = fmaxf(m, __shfl_xor(m, mk));
    const float e = expf(s - m);
    float sum = e;
#pragma unroll
    for (int mk = 1; mk <= 16; mk <<= 1) sum += __shfl_xor(sum, mk);
    const float w = e / sum;
    if (lane < 32) {
        awt_lds[lane] = w;
        out[(size_t)BB * 193 + (size_t)b * GG + lane] = w;   // at_wt
    }
    float wmax = w;
#pragma unroll
    for (int mk = 1; mk <= 16; mk <<= 1) wmax = fmaxf(wmax, __shfl_xor(wmax, mk));
    int idxc = (w == wmax) ? gl : 1000;                      // first-index tie-break
#pragma unroll
    for (int mk = 1; mk <= 16; mk <<= 1) idxc = min(idxc, __shfl_xor(idxc, mk));

    // ---- routing classifier (argmax over softmax == argmax over scores) ----
    const float cs0 = wmax * cls_w[0] + cls_b[0];
    const float cs1 = (wmax * cls_w[1] + cls_b[1]) + 0.5f;
    const int pred  = (cs1 > cs0) ? 1 : 0;

    __syncthreads();

    // ---- g_att: leader row or attention-weighted sum ----
    float gatt;
    if (pred == 1) {
        gatt = mem_lds[idxc * 68 + lane];
    } else {
        float acc = 0.f;
        for (int g = 0; g < GG; ++g)
            acc = fmaf(awt_lds[g], mem_lds[g * 68 + lane], acc);
        gatt = acc;
    }
    const float gp = group_table[(size_t)gidx * DD + lane]
                   + group_embedds[(size_t)gidx * DD + lane];
    const float gv = gatt + gp;
    const float el = gv * it;

    out[(size_t)b * 192 + lane]       = el;   // new_embeds[:, 0:64]
    out[(size_t)b * 192 + 64 + lane]  = gv;   // new_embeds[:, 64:128]
    out[(size_t)b * 192 + 128 + lane] = it;   // new_embeds[:, 128:192]

    __syncthreads();                           // mem_lds fully consumed; alias as ne_lds
    ne_lds[lane]        = el;
    ne_lds[64 + lane]   = gv;
    ne_lds[128 + lane]  = it;
    __syncthreads();

    // ---- predict MLP: 192 -> 8 (relu) -> 1 (sigmoid) ----
    const int j  = lane & 7;
    const int sg = lane >> 3;                  // 0..7, 24 inputs each
    float pacc = 0.f;
#pragma unroll
    for (int cc = 0; cc < 24; ++cc) {
        const int c = sg * 24 + cc;
        pacc = fmaf(ne_lds[c], pred_w1[c * 8 + j], pacc);
    }
    pacc += __shfl_xor(pacc, 8);
    pacc += __shfl_xor(pacc, 16);
    pacc += __shfl_xor(pacc, 32);
    const float ph = fmaxf(pacc + pred_b1[j], 0.f);
    float t = ph * pred_w2[j];
    t += __shfl_xor(t, 1);
    t += __shfl_xor(t, 2);
    t += __shfl_xor(t, 4);
    const float yv = 1.f / (1.f + expf(-(t + pred_b2[0])));

    if (lane == 0) {
        out[(size_t)BB * 192 + b] = yv;            // y
        out[(size_t)BB * 225 + b] = (float)pred;   // pred_cls (as f32)
    }
}

extern "C" void kernel_launch(void* const* d_in, const int* in_sizes, int n_in,
                              void* d_out, int out_size, void* d_ws, size_t ws_size,
                              hipStream_t stream) {
    const int*   group_inputs = (const int*)d_in[0];
    const int*   item_inputs  = (const int*)d_in[1];
    const int*   members      = (const int*)d_in[2];
    const float* user_table   = (const float*)d_in[3];
    const float* item_table   = (const float*)d_in[4];
    const float* group_table  = (const float*)d_in[5];
    const float* group_embedds= (const float*)d_in[6];
    const float* att_w1 = (const float*)d_in[7];
    const float* att_b1 = (const float*)d_in[8];
    const float* att_w2 = (const float*)d_in[9];
    const float* att_b2 = (const float*)d_in[10];
    const float* cls_w  = (const float*)d_in[11];
    const float* cls_b  = (const float*)d_in[12];
    const float* pred_w1 = (const float*)d_in[13];
    const float* pred_b1 = (const float*)d_in[14];
    const float* pred_w2 = (const float*)d_in[15];
    const float* pred_b2 = (const float*)d_in[16];
    float* out = (float*)d_out;

    hipLaunchKernelGGL(hhgr_kernel, dim3(BB), dim3(64), 0, stream,
                       group_inputs, item_inputs, members, user_table, item_table,
                       group_table, group_embedds, att_w1, att_b1, att_w2, att_b2,
                       cls_w, cls_b, pred_w1, pred_b1, pred_w2, pred_b2, out);
}

// Round 3
// 144.840 us; speedup vs baseline: 1.0411x; 1.0411x over previous
//
#include <hip/hip_runtime.h>

#define BB 8192
#define GG 32
#define DD 64

// ---- DPP cross-lane helpers (VALU pipe, rows of 16 lanes) ----
#define QUAD_XOR1 0xB1   // quad_perm [1,0,3,2]
#define QUAD_XOR2 0x4E   // quad_perm [2,3,0,1]
#define ROW_ROR4  0x124
#define ROW_ROR8  0x128

template<int CTRL>
__device__ __forceinline__ float dpp_mov(float x) {
    return __int_as_float(__builtin_amdgcn_update_dpp(
        __float_as_int(x), __float_as_int(x), CTRL, 0xF, 0xF, false));
}
// full sum over the 16-lane row, result in all 16 lanes
__device__ __forceinline__ float row16_sum(float x) {
    x += dpp_mov<QUAD_XOR1>(x);
    x += dpp_mov<QUAD_XOR2>(x);
    x += dpp_mov<ROW_ROR4>(x);
    x += dpp_mov<ROW_ROR8>(x);
    return x;
}
__device__ __forceinline__ float row16_max(float x) {
    x = fmaxf(x, dpp_mov<QUAD_XOR1>(x));
    x = fmaxf(x, dpp_mov<QUAD_XOR2>(x));
    x = fmaxf(x, dpp_mov<ROW_ROR4>(x));
    x = fmaxf(x, dpp_mov<ROW_ROR8>(x));
    return x;
}
template<int CTRL>
__device__ __forceinline__ int dpp_mov_i(int x) {
    return __builtin_amdgcn_update_dpp(x, x, CTRL, 0xF, 0xF, false);
}
__device__ __forceinline__ int row16_min_i(int x) {
    x = min(x, dpp_mov_i<QUAD_XOR1>(x));
    x = min(x, dpp_mov_i<QUAD_XOR2>(x));
    x = min(x, dpp_mov_i<ROW_ROR4>(x));
    x = min(x, dpp_mov_i<ROW_ROR8>(x));
    return x;
}
// reductions over the 32-lane half: row16 + xor16 (1 DS op)
__device__ __forceinline__ float half_sum(float x) { x = row16_sum(x); return x + __shfl_xor(x, 16); }
__device__ __forceinline__ float half_max(float x) { x = row16_max(x); return fmaxf(x, __shfl_xor(x, 16)); }
__device__ __forceinline__ int   half_min_i(int x) { x = row16_min_i(x); return min(x, __shfl_xor(x, 16)); }

__global__ __launch_bounds__(256)
void hhgr_kernel(const int* __restrict__ group_inputs,
                 const int* __restrict__ item_inputs,
                 const int* __restrict__ members,
                 const float* __restrict__ user_table,
                 const float* __restrict__ item_table,
                 const float* __restrict__ group_table,
                 const float* __restrict__ group_embedds,
                 const float* __restrict__ att_w1, const float* __restrict__ att_b1,
                 const float* __restrict__ att_w2, const float* __restrict__ att_b2,
                 const float* __restrict__ cls_w, const float* __restrict__ cls_b,
                 const float* __restrict__ pred_w1, const float* __restrict__ pred_b1,
                 const float* __restrict__ pred_w2, const float* __restrict__ pred_b2,
                 float* __restrict__ out)
{
    // LDS only for the (statistically dead) weighted-sum branch
    __shared__ float awt_s[8][32];
    __shared__ int   midx_s[8][32];

    const int tid  = threadIdx.x;
    const int m    = tid & 31;            // member index (= lane within half)
    const int slot = tid >> 5;            // 0..7: row slot within block
    const int wl   = tid & 63;            // lane within wave
    const int hw   = wl >> 5;             // half within wave
    const int b    = blockIdx.x * 8 + slot;

    const int midx = members[b * GG + m];         // coalesced
    const int iidx = item_inputs[b];
    const int gidx = group_inputs[b];

    // ---- gather my member's full row into 64 registers (16x dwordx4) ----
    float4 mr[16];
    {
        const float4* urow = (const float4*)(user_table + (size_t)midx * DD);
#pragma unroll
        for (int i = 0; i < 16; ++i) mr[i] = urow[i];
    }

    // ---- item half of layer 1, distributed: this lane covers k = 2m, 2m+1 ----
    float h[16];
    {
        const float2 it2 = *(const float2*)(item_table + (size_t)iidx * DD + 2 * m);
        const float4* wa = (const float4*)(att_w1 + (64 + 2 * m) * 16);
        const float4* wb = (const float4*)(att_w1 + (65 + 2 * m) * 16);
#pragma unroll
        for (int q4 = 0; q4 < 4; ++q4) {
            const float4 a  = wa[q4];
            const float4 bq = wb[q4];
            h[4 * q4 + 0] = fmaf(it2.y, bq.x, it2.x * a.x);
            h[4 * q4 + 1] = fmaf(it2.y, bq.y, it2.x * a.y);
            h[4 * q4 + 2] = fmaf(it2.y, bq.z, it2.x * a.z);
            h[4 * q4 + 3] = fmaf(it2.y, bq.w, it2.x * a.w);
        }
        // reduce each h[i] over the 32 lanes of this half; add b1
#pragma unroll
        for (int i = 0; i < 16; ++i)
            h[i] = half_sum(h[i]) + att_b1[i];
    }

    // ---- member half of layer 1: k-outer, SGPR-uniform weights ----
#pragma unroll
    for (int i = 0; i < 16; ++i) {
#pragma unroll
        for (int j = 0; j < 4; ++j) {
            const float mk = (j == 0) ? mr[i].x : (j == 1) ? mr[i].y
                           : (j == 2) ? mr[i].z : mr[i].w;
            const float* wr = att_w1 + (4 * i + j) * 16;   // uniform row -> s_load
#pragma unroll
            for (int oo = 0; oo < 16; ++oo)
                h[oo] = fmaf(mk, wr[oo], h[oo]);
        }
    }

    // ---- layer 2 + score ----
    float sc = att_b2[0];
#pragma unroll
    for (int oo = 0; oo < 16; ++oo)
        sc = fmaf(fmaxf(h[oo], 0.f), att_w2[oo], sc);

    // ---- softmax over the 32 members of this row ----
    const float smax = half_max(sc);
    const float e    = expf(sc - smax);
    const float ssum = half_sum(e);
    const float w    = e / ssum;
    out[(size_t)BB * 193 + (size_t)b * GG + m] = w;            // at_wt

    const float wmax = half_max(w);
    const int   idx  = half_min_i((w == wmax) ? m : 1000);     // first-max index

    // ---- routing classifier ----
    const float cs0 = fmaf(wmax, cls_w[0], cls_b[0]);
    const float cs1 = fmaf(wmax, cls_w[1], cls_b[1]) + 0.5f;
    const int pred  = (cs1 > cs0) ? 1 : 0;

    // ---- g_att (leader whp; weighted branch kept correct via LDS) ----
    float gA, gB;
    if (pred) {
        const int lmidx = __shfl(midx, hw * 32 + idx);
        const float* lrow = user_table + (size_t)lmidx * DD;   // L1/L2 hot
        gA = lrow[m];
        gB = lrow[m + 32];
    } else {
        awt_s[slot][m]  = w;
        midx_s[slot][m] = midx;
        __builtin_amdgcn_s_waitcnt(0);   // drain lgkm before half reads LDS back
        float accA = 0.f, accB = 0.f;
        for (int g = 0; g < GG; ++g) {
            const float wg = awt_s[slot][g];
            const float* grow = user_table + (size_t)midx_s[slot][g] * DD;
            accA = fmaf(wg, grow[m], accA);
            accB = fmaf(wg, grow[m + 32], accB);
        }
        gA = accA; gB = accB;
    }

    // ---- group-pure + elementwise + new_embeds outputs ----
    const float gpA = group_table[(size_t)gidx * DD + m]      + group_embedds[(size_t)gidx * DD + m];
    const float gpB = group_table[(size_t)gidx * DD + m + 32] + group_embedds[(size_t)gidx * DD + m + 32];
    const float itA = item_table[(size_t)iidx * DD + m];
    const float itB = item_table[(size_t)iidx * DD + m + 32];
    const float gvA = gA + gpA, gvB = gB + gpB;
    const float elA = gvA * itA, elB = gvB * itB;

    const size_t nb = (size_t)b * 192;
    out[nb + m]        = elA;  out[nb + 32 + m]  = elB;   // elem
    out[nb + 64 + m]   = gvA;  out[nb + 96 + m]  = gvB;   // g
    out[nb + 128 + m]  = itA;  out[nb + 160 + m] = itB;   // item

    // ---- predict MLP: 192 -> 8 (relu) -> 1 (sigmoid), distributed over lanes ----
    float p8[8];
#pragma unroll
    for (int j = 0; j < 8; ++j) p8[j] = 0.f;

    {
        const float vals[6] = { elA, elB, gvA, gvB, itA, itB };
        const int   cols[6] = { m, m + 32, 64 + m, 96 + m, 128 + m, 160 + m };
#pragma unroll
        for (int t = 0; t < 6; ++t) {
            const float4* wr = (const float4*)(pred_w1 + cols[t] * 8);
            const float4 w0 = wr[0], w1v = wr[1];
            p8[0] = fmaf(vals[t], w0.x, p8[0]);
            p8[1] = fmaf(vals[t], w0.y, p8[1]);
            p8[2] = fmaf(vals[t], w0.z, p8[2]);
            p8[3] = fmaf(vals[t], w0.w, p8[3]);
            p8[4] = fmaf(vals[t], w1v.x, p8[4]);
            p8[5] = fmaf(vals[t], w1v.y, p8[5]);
            p8[6] = fmaf(vals[t], w1v.z, p8[6]);
            p8[7] = fmaf(vals[t], w1v.w, p8[7]);
        }
    }
#pragma unroll
    for (int j = 0; j < 8; ++j)
        p8[j] = half_sum(p8[j]) + pred_b1[j];

    float t2 = pred_b2[0];
#pragma unroll
    for (int j = 0; j < 8; ++j)
        t2 = fmaf(fmaxf(p8[j], 0.f), pred_w2[j], t2);
    const float yv = 1.f / (1.f + expf(-t2));

    if (m == 0) {
        out[(size_t)BB * 192 + b] = yv;            // y
        out[(size_t)BB * 225 + b] = (float)pred;   // pred_cls
    }
}

extern "C" void kernel_launch(void* const* d_in, const int* in_sizes, int n_in,
                              void* d_out, int out_size, void* d_ws, size_t ws_size,
                              hipStream_t stream) {
    const int*   group_inputs  = (const int*)d_in[0];
    const int*   item_inputs   = (const int*)d_in[1];
    const int*   members       = (const int*)d_in[2];
    const float* user_table    = (const float*)d_in[3];
    const float* item_table    = (const float*)d_in[4];
    const float* group_table   = (const float*)d_in[5];
    const float* group_embedds = (const float*)d_in[6];
    const float* att_w1  = (const float*)d_in[7];
    const float* att_b1  = (const float*)d_in[8];
    const float* att_w2  = (const float*)d_in[9];
    const float* att_b2  = (const float*)d_in[10];
    const float* cls_w   = (const float*)d_in[11];
    const float* cls_b   = (const float*)d_in[12];
    const float* pred_w1 = (const float*)d_in[13];
    const float* pred_b1 = (const float*)d_in[14];
    const float* pred_w2 = (const float*)d_in[15];
    const float* pred_b2 = (const float*)d_in[16];
    float* out = (float*)d_out;

    hipLaunchKernelGGL(hhgr_kernel, dim3(BB / 8), dim3(256), 0, stream,
                       group_inputs, item_inputs, members, user_table, item_table,
                       group_table, group_embedds, att_w1, att_b1, att_w2, att_b2,
                       cls_w, cls_b, pred_w1, pred_b1, pred_w2, pred_b2, out);
}